// Round 3
// baseline (141.477 us; speedup 1.0000x reference)
//
#include <hip/hip_runtime.h>
#include <math.h>

#define KNN  20
#define INFK 0xFFFFFFFFu

// wave-wide min of packed u32 keys (lexicographic (dist,idx) since dist>=0)
__device__ __forceinline__ unsigned wave_min_u32(unsigned k) {
    #pragma unroll
    for (int off = 32; off >= 1; off >>= 1) {
        unsigned o = (unsigned)__shfl_xor((int)k, off, 64);
        k = (o < k) ? o : k;
    }
    return k;
}

// branchless sorted insert (ascending) into 8-reg list via min/max pairs
__device__ __forceinline__ void insert8(unsigned (&cd)[8], unsigned key) {
    #pragma unroll
    for (int i = 0; i < 8; ++i) {
        const unsigned lo = (cd[i] < key) ? cd[i] : key;
        const unsigned hi = (cd[i] < key) ? key : cd[i];
        cd[i] = lo; key = hi;
    }
}

// canonical ascending-d fma chain (all sq/dot use this -> exact diagonal zero)
__device__ __forceinline__ float dot16(const float4& o0, const float4& o1,
                                       const float4& o2, const float4& o3,
                                       const float4& a0, const float4& a1,
                                       const float4& a2, const float4& a3) {
    float d = 0.f;
    d = fmaf(o0.x, a0.x, d); d = fmaf(o0.y, a0.y, d); d = fmaf(o0.z, a0.z, d); d = fmaf(o0.w, a0.w, d);
    d = fmaf(o1.x, a1.x, d); d = fmaf(o1.y, a1.y, d); d = fmaf(o1.z, a1.z, d); d = fmaf(o1.w, a1.w, d);
    d = fmaf(o2.x, a2.x, d); d = fmaf(o2.y, a2.y, d); d = fmaf(o2.z, a2.z, d); d = fmaf(o2.w, a2.w, d);
    d = fmaf(o3.x, a3.x, d); d = fmaf(o3.y, a3.y, d); d = fmaf(o3.z, a3.z, d); d = fmaf(o3.w, a3.w, d);
    return d;
}

// ---------------------------------------------------------------------------
// Stage 1: KNN on raw 16-d points + wFM -> R[b,n,16], sqr[b,n] = ||R||^2.
// Also initializes out[b,:] = b_cls (stage2 accumulates atomically on top).
// ---------------------------------------------------------------------------
__global__ __launch_bounds__(256, 8)
void stage1_kernel(const float* __restrict__ x, const float* __restrict__ w_fm1,
                   const float* __restrict__ b_cls,
                   float* __restrict__ R, float* __restrict__ sqr,
                   float* __restrict__ out) {
    __shared__ unsigned sk[4 * 576];      // per-wave 64 x 9 (stride 9 -> conflict-free)
    __shared__ unsigned nbrS[4 * KNN];
    __shared__ float    ssq[512];
    __shared__ float    swn[KNN];
    const int tid   = threadIdx.x;
    const int bidx  = blockIdx.x;
    const int batch = bidx >> 7;          // 128 blocks per batch
    const float* xb = x + (size_t)batch * 8192;

    // classifier bias init, once per batch (stream-ordered before stage2 atomics)
    if ((bidx & 127) == 0 && tid < 40)
        out[batch * 40 + tid] = b_cls[tid];

    // softmax(w_fm1): threads 0..19 each redundantly compute the full softmax
    if (tid < KNN) {
        float v[KNN]; float mx = -__builtin_inff();
        #pragma unroll
        for (int k = 0; k < KNN; ++k) { v[k] = w_fm1[k]; mx = fmaxf(mx, v[k]); }
        float s = 0.f;
        #pragma unroll
        for (int k = 0; k < KNN; ++k) { v[k] = __expf(v[k] - mx); s += v[k]; }
        swn[tid] = v[tid] / s;
    }

    // per-point squared norms (canonical chain)
    for (int m = tid; m < 512; m += 256) {
        const float4* p = (const float4*)(xb + m * 16);
        const float4 a0 = p[0], a1 = p[1], a2 = p[2], a3 = p[3];
        ssq[m] = dot16(a0, a1, a2, a3, a0, a1, a2, a3);
    }
    __syncthreads();

    const int t = tid & 63, w = tid >> 6;
    const int row = bidx * 4 + w;
    const int n = row & 511;

    const float4* xn4 = (const float4*)(xb + n * 16);
    const float4 o0 = xn4[0], o1 = xn4[1], o2 = xn4[2], o3 = xn4[3];
    const float sqn = ssq[n];

    unsigned cd[8];
    #pragma unroll
    for (int i = 0; i < 8; ++i) cd[i] = INFK;

    #pragma unroll
    for (int j = 0; j < 8; ++j) {
        const int m = j * 64 + t;
        const float4* xm4 = (const float4*)(xb + m * 16);
        const float4 a0 = xm4[0], a1 = xm4[1], a2 = xm4[2], a3 = xm4[3];
        const float dot = dot16(o0, o1, o2, o3, a0, a1, a2, a3);
        float vd = fmaxf(sqn + ssq[m] - 2.f * dot, 0.f);   // exact 0 at m==n
        insert8(cd, (__float_as_uint(vd) & 0xFFFFFE00u) | (unsigned)m);
    }

    unsigned* skw = sk + w * 576;
    #pragma unroll
    for (int i = 1; i < 8; ++i) skw[t * 9 + i] = cd[i];

    unsigned cur = cd[0];
    int h = 0;
    #pragma unroll
    for (int r = 0; r < KNN; ++r) {
        const unsigned bk = wave_min_u32(cur);
        if (t == 0) nbrS[w * KNN + r] = bk & 511u;
        if (cur == bk) { ++h; cur = (h < 8) ? skw[t * 9 + h] : INFK; }
    }

    // gather 20 neighbor rows (320 floats) into 5 regs/lane
    float nrf[5];
    #pragma unroll
    for (int j = 0; j < 5; ++j) {
        const int e = j * 64 + t;
        nrf[j] = xb[nbrS[w * KNN + (e >> 4)] * 16 + (e & 15)];
    }
    // R[d] = sum_k swn[k] * NR[k][d] for lane d = t < 16
    float racc = 0.f;
    #pragma unroll
    for (int k = 0; k < KNN; ++k) {
        const float nr = __shfl(nrf[k >> 2], (k * 16 + t) & 63, 64);
        racc = fmaf(swn[k], nr, racc);
    }
    if (t < 16) R[(size_t)row * 16 + t] = racc;
    // ||R||^2 with the same ascending-d chain as stage-2's dot
    float s2 = 0.f;
    #pragma unroll
    for (int d = 0; d < 16; ++d) {
        const float rv = __int_as_float(__builtin_amdgcn_readlane(__float_as_int(racc), d));
        s2 = fmaf(rv, rv, s2);
    }
    if (t == 0) sqr[row] = s2;
}

// ---------------------------------------------------------------------------
// Stage 2: in-block Q precompute, KNN on R, fused wFM2.mix2 + manifold dist +
// pool + classifier atomic accumulation. No intermediate global tensors.
// ---------------------------------------------------------------------------
__global__ __launch_bounds__(256, 8)
void stage2_kernel(const float* __restrict__ Rg, const float* __restrict__ sqr,
                   const float* __restrict__ w_fm2, const float* __restrict__ w_mix1,
                   const float* __restrict__ w_mix2, const float* __restrict__ m_last,
                   const float* __restrict__ w_cls, float* __restrict__ out) {
    __shared__ unsigned sk[4 * 576];      // phase A reuses this as wcs[30][21]
    __shared__ unsigned nbrS[4 * KNN];
    __shared__ float    sQ[KNN * 50];
    __shared__ float    sM[16 * 50];
    __shared__ float    pool4[4];
    const int tid   = threadIdx.x;
    const int bidx  = blockIdx.x;
    const int batch = bidx >> 7;
    const float* Rb = Rg + (size_t)batch * 8192;
    const float* sb = sqr + batch * 512;

    // phase A: wcs[c][k] = softmax(w_fm2)[c][k] * w_mix1[c]  (in sk space)
    float* wcs = (float*)sk;
    if (tid < 30) {
        float wr[KNN]; float mx = -__builtin_inff();
        #pragma unroll
        for (int k = 0; k < KNN; ++k) { wr[k] = w_fm2[tid * KNN + k]; mx = fmaxf(mx, wr[k]); }
        float s = 0.f;
        #pragma unroll
        for (int k = 0; k < KNN; ++k) { wr[k] = __expf(wr[k] - mx); s += wr[k]; }
        const float scale = w_mix1[tid] / s;
        #pragma unroll
        for (int k = 0; k < KNN; ++k) wcs[tid * 21 + k] = wr[k] * scale;
    }
    for (int e = tid; e < 16 * 50; e += 256) sM[e] = m_last[e];
    __syncthreads();
    // Q[k][f] = sum_c wcs[c][k] * w_mix2[c][f]
    for (int e = tid; e < KNN * 50; e += 256) {
        const int k = e / 50, f = e - k * 50;
        float acc = 0.f;
        #pragma unroll
        for (int c = 0; c < 30; ++c)
            acc = fmaf(wcs[c * 21 + k], w_mix2[c * 50 + f], acc);
        sQ[e] = acc;
    }
    __syncthreads();                       // wcs dead; sk free for KNN

    // phase B: KNN on R
    const int t = tid & 63, w = tid >> 6;
    const int row = bidx * 4 + w;
    const int n = row & 511;

    const float4* rn4 = (const float4*)(Rb + n * 16);
    const float4 o0 = rn4[0], o1 = rn4[1], o2 = rn4[2], o3 = rn4[3];
    const float sqn = sb[n];

    unsigned cd[8];
    #pragma unroll
    for (int i = 0; i < 8; ++i) cd[i] = INFK;

    #pragma unroll
    for (int j = 0; j < 8; ++j) {
        const int m = j * 64 + t;
        const float4* rm4 = (const float4*)(Rb + m * 16);
        const float4 a0 = rm4[0], a1 = rm4[1], a2 = rm4[2], a3 = rm4[3];
        const float dot = dot16(o0, o1, o2, o3, a0, a1, a2, a3);
        float vd = fmaxf(sqn + sb[m] - 2.f * dot, 0.f);    // exact 0 at m==n
        insert8(cd, (__float_as_uint(vd) & 0xFFFFFE00u) | (unsigned)m);
    }

    unsigned* skw = sk + w * 576;
    #pragma unroll
    for (int i = 1; i < 8; ++i) skw[t * 9 + i] = cd[i];

    unsigned cur = cd[0];
    int h = 0;
    #pragma unroll
    for (int r = 0; r < KNN; ++r) {
        const unsigned bk = wave_min_u32(cur);
        if (t == 0) nbrS[w * KNN + r] = bk & 511u;
        if (cur == bk) { ++h; cur = (h < 8) ? skw[t * 9 + h] : INFK; }
    }

    float nrf[5];
    #pragma unroll
    for (int j = 0; j < 5; ++j) {
        const int e = j * 64 + t;
        nrf[j] = Rb[nbrS[w * KNN + (e >> 4)] * 16 + (e & 15)];
    }

    // phase C: lane f<50: v[d] = sum_k NR[k][d]*Q[k][f]; dist = sqrt(sum_d (v-m)^2 + 1e-8)
    const int f = (t < 50) ? t : 49;
    float q[KNN];
    #pragma unroll
    for (int k = 0; k < KNN; ++k) q[k] = sQ[k * 50 + f];
    float acc = 0.f;
    #pragma unroll
    for (int d = 0; d < 16; ++d) {
        float v = 0.f;
        #pragma unroll
        for (int k = 0; k < KNN; ++k) {
            const int e = k * 16 + d;
            const float nr = __int_as_float(
                __builtin_amdgcn_readlane(__float_as_int(nrf[e >> 6]), e & 63));
            v = fmaf(nr, q[k], v);
        }
        v -= sM[d * 50 + f];
        acc = fmaf(v, v, acc);
    }
    float dist50 = (t < 50) ? sqrtf(acc + 1e-8f) : 0.f;
    #pragma unroll
    for (int off = 32; off >= 1; off >>= 1) dist50 += __shfl_xor(dist50, off, 64);
    if (t == 0) pool4[w] = dist50 * (1.0f / 50.0f);
    __syncthreads();

    // classifier: one wave-op of atomics per block (4 rows pre-reduced)
    if (tid < 40) {
        const int n0 = (bidx * 4) & 511;
        float a = 0.f;
        #pragma unroll
        for (int i = 0; i < 4; ++i)
            a = fmaf(pool4[i], w_cls[(n0 + i) * 40 + tid], a);
        unsafeAtomicAdd(&out[batch * 40 + tid], a);
    }
}

extern "C" void kernel_launch(void* const* d_in, const int* in_sizes, int n_in,
                              void* d_out, int out_size, void* d_ws, size_t ws_size,
                              hipStream_t stream) {
    const float* x      = (const float*)d_in[0];
    const float* w_fm1  = (const float*)d_in[1];
    const float* w_mix1 = (const float*)d_in[2];
    const float* w_fm2  = (const float*)d_in[3];
    const float* w_mix2 = (const float*)d_in[4];
    const float* m_last = (const float*)d_in[5];
    const float* w_cls  = (const float*)d_in[6];
    const float* b_cls  = (const float*)d_in[7];
    float* out = (float*)d_out;

    float* ws   = (float*)d_ws;
    float* R    = ws;                  // 131072 floats
    float* sqrb = ws + 131072;         // 8192 floats

    stage1_kernel<<<2048, 256, 0, stream>>>(x, w_fm1, b_cls, R, sqrb, out);
    stage2_kernel<<<2048, 256, 0, stream>>>(R, sqrb, w_fm2, w_mix1, w_mix2,
                                            m_last, w_cls, out);
}

// Round 4
// 132.929 us; speedup vs baseline: 1.0643x; 1.0643x over previous
//
#include <hip/hip_runtime.h>
#include <math.h>

#define KNN  20
#define INFK 0xFFFFFFFFu

// ---- DPP wave64 min-reduction (u32), result broadcast via SGPR -------------
// row_shr accumulates toward the last lane of each 16-row; bcast15/31 cross
// rows; lane 63 ends with the global min. old=v => invalid/masked lanes no-op.
#define DPP_MIN_STEP(v, ctrl, rm)                                              \
    {                                                                          \
        unsigned _t = (unsigned)__builtin_amdgcn_update_dpp(                   \
            (int)(v), (int)(v), (ctrl), (rm), 0xf, false);                     \
        (v) = ((v) < _t) ? (v) : _t;                                           \
    }

__device__ __forceinline__ unsigned wave_min_bcast(unsigned v) {
    DPP_MIN_STEP(v, 0x111, 0xf);   // row_shr:1
    DPP_MIN_STEP(v, 0x112, 0xf);   // row_shr:2
    DPP_MIN_STEP(v, 0x114, 0xf);   // row_shr:4
    DPP_MIN_STEP(v, 0x118, 0xf);   // row_shr:8
    DPP_MIN_STEP(v, 0x142, 0xa);   // row_bcast:15 (rows 1,3)
    DPP_MIN_STEP(v, 0x143, 0xc);   // row_bcast:31 (rows 2,3)
    return (unsigned)__builtin_amdgcn_readlane((int)v, 63);  // uniform
}

// branchless sorted insert (ascending) into 8-reg list via min/max pairs
__device__ __forceinline__ void insert8(unsigned (&cd)[8], unsigned key) {
    #pragma unroll
    for (int i = 0; i < 8; ++i) {
        const unsigned lo = (cd[i] < key) ? cd[i] : key;
        const unsigned hi = (cd[i] < key) ? key : cd[i];
        cd[i] = lo; key = hi;
    }
}

// canonical 4-chain dot product; EVERY sq/dot in the pipeline uses this same
// function so the m==n diagonal gives exactly s+s-2s == 0.
__device__ __forceinline__ float dot16(const float4& o0, const float4& o1,
                                       const float4& o2, const float4& o3,
                                       const float4& a0, const float4& a1,
                                       const float4& a2, const float4& a3) {
    float d0 = 0.f, d1 = 0.f, d2 = 0.f, d3 = 0.f;
    d0 = fmaf(o0.x, a0.x, d0); d0 = fmaf(o0.y, a0.y, d0); d0 = fmaf(o0.z, a0.z, d0); d0 = fmaf(o0.w, a0.w, d0);
    d1 = fmaf(o1.x, a1.x, d1); d1 = fmaf(o1.y, a1.y, d1); d1 = fmaf(o1.z, a1.z, d1); d1 = fmaf(o1.w, a1.w, d1);
    d2 = fmaf(o2.x, a2.x, d2); d2 = fmaf(o2.y, a2.y, d2); d2 = fmaf(o2.z, a2.z, d2); d2 = fmaf(o2.w, a2.w, d2);
    d3 = fmaf(o3.x, a3.x, d3); d3 = fmaf(o3.y, a3.y, d3); d3 = fmaf(o3.z, a3.z, d3); d3 = fmaf(o3.w, a3.w, d3);
    return (d0 + d1) + (d2 + d3);
}

// ---------------------------------------------------------------------------
// Stage 1: KNN on raw 16-d points + wFM -> R[b,n,16], sqr[b,n] = ||R||^2.
// Also initializes out[b,:] = b_cls (stage2 accumulates atomically on top).
// ---------------------------------------------------------------------------
__global__ __launch_bounds__(256)
void stage1_kernel(const float* __restrict__ x, const float* __restrict__ w_fm1,
                   const float* __restrict__ b_cls,
                   float* __restrict__ R, float* __restrict__ sqr,
                   float* __restrict__ out) {
    __shared__ unsigned sk[4 * 576];      // per-wave 64 x 9 (stride 9 -> conflict-free)
    __shared__ unsigned nbrS[4 * KNN];
    __shared__ float    ssq[512];
    __shared__ float    swn[KNN];
    const int tid   = threadIdx.x;
    const int bidx  = blockIdx.x;
    const int batch = bidx >> 7;          // 128 blocks per batch
    const float* xb = x + (size_t)batch * 8192;

    if ((bidx & 127) == 0 && tid < 40)
        out[batch * 40 + tid] = b_cls[tid];

    if (tid < KNN) {
        float v[KNN]; float mx = -__builtin_inff();
        #pragma unroll
        for (int k = 0; k < KNN; ++k) { v[k] = w_fm1[k]; mx = fmaxf(mx, v[k]); }
        float s = 0.f;
        #pragma unroll
        for (int k = 0; k < KNN; ++k) { v[k] = __expf(v[k] - mx); s += v[k]; }
        swn[tid] = v[tid] / s;
    }

    for (int m = tid; m < 512; m += 256) {
        const float4* p = (const float4*)(xb + m * 16);
        const float4 a0 = p[0], a1 = p[1], a2 = p[2], a3 = p[3];
        ssq[m] = dot16(a0, a1, a2, a3, a0, a1, a2, a3);
    }
    __syncthreads();

    const int t = tid & 63, w = tid >> 6;
    const int row = bidx * 4 + w;
    const int n = row & 511;

    const float4* xn4 = (const float4*)(xb + n * 16);
    const float4 o0 = xn4[0], o1 = xn4[1], o2 = xn4[2], o3 = xn4[3];
    const float sqn = ssq[n];

    unsigned cd[8];
    #pragma unroll
    for (int i = 0; i < 8; ++i) cd[i] = INFK;

    #pragma unroll
    for (int j = 0; j < 8; ++j) {
        const int m = j * 64 + t;
        const float4* xm4 = (const float4*)(xb + m * 16);
        const float4 a0 = xm4[0], a1 = xm4[1], a2 = xm4[2], a3 = xm4[3];
        const float dot = dot16(o0, o1, o2, o3, a0, a1, a2, a3);
        float vd = fmaxf(sqn + ssq[m] - 2.f * dot, 0.f);   // exact 0 at m==n
        insert8(cd, (__float_as_uint(vd) & 0xFFFFFE00u) | (unsigned)m);
    }

    unsigned* skw = sk + w * 576;
    #pragma unroll
    for (int i = 1; i < 8; ++i) skw[t * 9 + i] = cd[i];

    unsigned cur = cd[0];
    int h = 0;
    #pragma unroll
    for (int r = 0; r < KNN; ++r) {
        const unsigned bk = wave_min_bcast(cur);           // uniform
        if (t == 0) nbrS[w * KNN + r] = bk & 511u;
        if (cur == bk) { ++h; cur = (h < 8) ? skw[t * 9 + h] : INFK; }
    }

    // gather 20 neighbor rows (320 floats) into 5 regs/lane
    float nrf[5];
    #pragma unroll
    for (int j = 0; j < 5; ++j) {
        const int e = j * 64 + t;
        nrf[j] = xb[nbrS[w * KNN + (e >> 4)] * 16 + (e & 15)];
    }
    // R[d] = sum_k swn[k] * NR[k][d] for lane d = t < 16
    float racc = 0.f;
    #pragma unroll
    for (int k = 0; k < KNN; ++k) {
        const float nr = __shfl(nrf[k >> 2], (k * 16 + t) & 63, 64);
        racc = fmaf(swn[k], nr, racc);
    }
    if (t < 16) R[(size_t)row * 16 + t] = racc;
    // ||R||^2 with the SAME 4-chain grouping as dot16 (stage-2 diag -> exact 0)
    float p0 = 0.f, p1 = 0.f, p2 = 0.f, p3 = 0.f;
    #pragma unroll
    for (int d = 0; d < 4; ++d) {
        const float rv = __int_as_float(__builtin_amdgcn_readlane(__float_as_int(racc), d));
        p0 = fmaf(rv, rv, p0);
    }
    #pragma unroll
    for (int d = 4; d < 8; ++d) {
        const float rv = __int_as_float(__builtin_amdgcn_readlane(__float_as_int(racc), d));
        p1 = fmaf(rv, rv, p1);
    }
    #pragma unroll
    for (int d = 8; d < 12; ++d) {
        const float rv = __int_as_float(__builtin_amdgcn_readlane(__float_as_int(racc), d));
        p2 = fmaf(rv, rv, p2);
    }
    #pragma unroll
    for (int d = 12; d < 16; ++d) {
        const float rv = __int_as_float(__builtin_amdgcn_readlane(__float_as_int(racc), d));
        p3 = fmaf(rv, rv, p3);
    }
    if (t == 0) sqr[row] = (p0 + p1) + (p2 + p3);
}

// ---------------------------------------------------------------------------
// Stage 2: in-block Q precompute, KNN on R, fused wFM2.mix2 + manifold dist +
// pool + classifier atomic accumulation.
// ---------------------------------------------------------------------------
__global__ __launch_bounds__(256)
void stage2_kernel(const float* __restrict__ Rg, const float* __restrict__ sqr,
                   const float* __restrict__ w_fm2, const float* __restrict__ w_mix1,
                   const float* __restrict__ w_mix2, const float* __restrict__ m_last,
                   const float* __restrict__ w_cls, float* __restrict__ out) {
    __shared__ unsigned sk[4 * 576];      // phase A reuses this as wcs[30][21]
    __shared__ unsigned nbrS[4 * KNN];
    __shared__ float    sQ[KNN * 50];
    __shared__ float    sM[16 * 50];
    __shared__ float    ssq2[512];
    __shared__ float    pool4[4];
    const int tid   = threadIdx.x;
    const int bidx  = blockIdx.x;
    const int batch = bidx >> 7;
    const float* Rb = Rg + (size_t)batch * 8192;
    const float* sb = sqr + batch * 512;

    // phase A: wcs[c][k] = softmax(w_fm2)[c][k] * w_mix1[c]  (in sk space)
    float* wcs = (float*)sk;
    if (tid < 30) {
        float wr[KNN]; float mx = -__builtin_inff();
        #pragma unroll
        for (int k = 0; k < KNN; ++k) { wr[k] = w_fm2[tid * KNN + k]; mx = fmaxf(mx, wr[k]); }
        float s = 0.f;
        #pragma unroll
        for (int k = 0; k < KNN; ++k) { wr[k] = __expf(wr[k] - mx); s += wr[k]; }
        const float scale = w_mix1[tid] / s;
        #pragma unroll
        for (int k = 0; k < KNN; ++k) wcs[tid * 21 + k] = wr[k] * scale;
    }
    for (int e = tid; e < 16 * 50; e += 256) sM[e] = m_last[e];
    for (int m = tid; m < 512; m += 256) ssq2[m] = sb[m];
    __syncthreads();
    for (int e = tid; e < KNN * 50; e += 256) {
        const int k = e / 50, f = e - k * 50;
        float acc = 0.f;
        #pragma unroll
        for (int c = 0; c < 30; ++c)
            acc = fmaf(wcs[c * 21 + k], w_mix2[c * 50 + f], acc);
        sQ[e] = acc;
    }
    __syncthreads();                       // wcs dead; sk free for KNN

    // phase B: KNN on R
    const int t = tid & 63, w = tid >> 6;
    const int row = bidx * 4 + w;
    const int n = row & 511;

    const float4* rn4 = (const float4*)(Rb + n * 16);
    const float4 o0 = rn4[0], o1 = rn4[1], o2 = rn4[2], o3 = rn4[3];
    const float sqn = ssq2[n];

    unsigned cd[8];
    #pragma unroll
    for (int i = 0; i < 8; ++i) cd[i] = INFK;

    #pragma unroll
    for (int j = 0; j < 8; ++j) {
        const int m = j * 64 + t;
        const float4* rm4 = (const float4*)(Rb + m * 16);
        const float4 a0 = rm4[0], a1 = rm4[1], a2 = rm4[2], a3 = rm4[3];
        const float dot = dot16(o0, o1, o2, o3, a0, a1, a2, a3);
        float vd = fmaxf(sqn + ssq2[m] - 2.f * dot, 0.f);  // exact 0 at m==n
        insert8(cd, (__float_as_uint(vd) & 0xFFFFFE00u) | (unsigned)m);
    }

    unsigned* skw = sk + w * 576;
    #pragma unroll
    for (int i = 1; i < 8; ++i) skw[t * 9 + i] = cd[i];

    unsigned cur = cd[0];
    int h = 0;
    #pragma unroll
    for (int r = 0; r < KNN; ++r) {
        const unsigned bk = wave_min_bcast(cur);           // uniform
        if (t == 0) nbrS[w * KNN + r] = bk & 511u;
        if (cur == bk) { ++h; cur = (h < 8) ? skw[t * 9 + h] : INFK; }
    }

    float nrf[5];
    #pragma unroll
    for (int j = 0; j < 5; ++j) {
        const int e = j * 64 + t;
        nrf[j] = Rb[nbrS[w * KNN + (e >> 4)] * 16 + (e & 15)];
    }

    // phase C: lane f<50: v[d] = sum_k NR[k][d]*Q[k][f]; dist = sqrt(sum (v-m)^2 + 1e-8)
    const int f = (t < 50) ? t : 49;
    float q[KNN];
    #pragma unroll
    for (int k = 0; k < KNN; ++k) q[k] = sQ[k * 50 + f];
    float acc = 0.f;
    #pragma unroll
    for (int d = 0; d < 16; ++d) {
        float v = 0.f;
        #pragma unroll
        for (int k = 0; k < KNN; ++k) {
            const int e = k * 16 + d;
            const float nr = __int_as_float(
                __builtin_amdgcn_readlane(__float_as_int(nrf[e >> 6]), e & 63));
            v = fmaf(nr, q[k], v);
        }
        v -= sM[d * 50 + f];
        acc = fmaf(v, v, acc);
    }
    float dist50 = (t < 50) ? sqrtf(acc + 1e-8f) : 0.f;
    #pragma unroll
    for (int off = 32; off >= 1; off >>= 1) dist50 += __shfl_xor(dist50, off, 64);
    if (t == 0) pool4[w] = dist50 * (1.0f / 50.0f);
    __syncthreads();

    // classifier: one wave of atomics per block (4 rows pre-reduced)
    if (tid < 40) {
        const int n0 = (bidx * 4) & 511;
        float a = 0.f;
        #pragma unroll
        for (int i = 0; i < 4; ++i)
            a = fmaf(pool4[i], w_cls[(n0 + i) * 40 + tid], a);
        unsafeAtomicAdd(&out[batch * 40 + tid], a);
    }
}

extern "C" void kernel_launch(void* const* d_in, const int* in_sizes, int n_in,
                              void* d_out, int out_size, void* d_ws, size_t ws_size,
                              hipStream_t stream) {
    const float* x      = (const float*)d_in[0];
    const float* w_fm1  = (const float*)d_in[1];
    const float* w_mix1 = (const float*)d_in[2];
    const float* w_fm2  = (const float*)d_in[3];
    const float* w_mix2 = (const float*)d_in[4];
    const float* m_last = (const float*)d_in[5];
    const float* w_cls  = (const float*)d_in[6];
    const float* b_cls  = (const float*)d_in[7];
    float* out = (float*)d_out;

    float* ws   = (float*)d_ws;
    float* R    = ws;                  // 131072 floats
    float* sqrb = ws + 131072;         // 8192 floats

    stage1_kernel<<<2048, 256, 0, stream>>>(x, w_fm1, b_cls, R, sqrb, out);
    stage2_kernel<<<2048, 256, 0, stream>>>(R, sqrb, w_fm2, w_mix1, w_mix2,
                                            m_last, w_cls, out);
}

// Round 5
// 122.516 us; speedup vs baseline: 1.1548x; 1.0850x over previous
//
#include <hip/hip_runtime.h>
#include <math.h>

#define KNN  20
#define INFK 0xFFFFFFFFu

// ---- DPP wave64 min-reduction (u32), result broadcast via readlane ---------
#define DPP_MIN_STEP(v, ctrl, rm)                                              \
    {                                                                          \
        unsigned _t = (unsigned)__builtin_amdgcn_update_dpp(                   \
            (int)(v), (int)(v), (ctrl), (rm), 0xf, false);                     \
        (v) = ((v) < _t) ? (v) : _t;                                           \
    }

__device__ __forceinline__ unsigned wave_min_bcast(unsigned v) {
    DPP_MIN_STEP(v, 0x111, 0xf);   // row_shr:1
    DPP_MIN_STEP(v, 0x112, 0xf);   // row_shr:2
    DPP_MIN_STEP(v, 0x114, 0xf);   // row_shr:4
    DPP_MIN_STEP(v, 0x118, 0xf);   // row_shr:8
    DPP_MIN_STEP(v, 0x142, 0xa);   // row_bcast:15 (rows 1,3)
    DPP_MIN_STEP(v, 0x143, 0xc);   // row_bcast:31 (rows 2,3)
    return (unsigned)__builtin_amdgcn_readlane((int)v, 63);  // uniform
}

// branchless sorted insert (ascending) into 8-reg list via min/max pairs
__device__ __forceinline__ void insert8(unsigned (&cd)[8], unsigned key) {
    #pragma unroll
    for (int i = 0; i < 8; ++i) {
        const unsigned lo = (cd[i] < key) ? cd[i] : key;
        const unsigned hi = (cd[i] < key) ? key : cd[i];
        cd[i] = lo; key = hi;
    }
}

// 20-round all-register merge: per round take the wave-wide min, the winning
// lane shifts its register list down (cndmask, no LDS on the critical path).
// Lane r ends holding neighbor index r in nbrv.
__device__ __forceinline__ int merge20(unsigned (&cd)[8], int t) {
    int nbrv = 0;
    #pragma unroll
    for (int r = 0; r < KNN; ++r) {
        const unsigned bk = wave_min_bcast(cd[0]);
        nbrv = (t == r) ? (int)(bk & 511u) : nbrv;
        const bool win = (cd[0] == bk);
        #pragma unroll
        for (int i = 0; i < 7; ++i) cd[i] = win ? cd[i + 1] : cd[i];
        cd[7] = win ? INFK : cd[7];
    }
    return nbrv;
}

// canonical 4-chain dot; EVERY sq/dot uses this -> m==n diagonal exactly 0
__device__ __forceinline__ float dot16(const float4& o0, const float4& o1,
                                       const float4& o2, const float4& o3,
                                       const float4& a0, const float4& a1,
                                       const float4& a2, const float4& a3) {
    float d0 = 0.f, d1 = 0.f, d2 = 0.f, d3 = 0.f;
    d0 = fmaf(o0.x, a0.x, d0); d0 = fmaf(o0.y, a0.y, d0); d0 = fmaf(o0.z, a0.z, d0); d0 = fmaf(o0.w, a0.w, d0);
    d1 = fmaf(o1.x, a1.x, d1); d1 = fmaf(o1.y, a1.y, d1); d1 = fmaf(o1.z, a1.z, d1); d1 = fmaf(o1.w, a1.w, d1);
    d2 = fmaf(o2.x, a2.x, d2); d2 = fmaf(o2.y, a2.y, d2); d2 = fmaf(o2.z, a2.z, d2); d2 = fmaf(o2.w, a2.w, d2);
    d3 = fmaf(o3.x, a3.x, d3); d3 = fmaf(o3.y, a3.y, d3); d3 = fmaf(o3.z, a3.z, d3); d3 = fmaf(o3.w, a3.w, d3);
    return (d0 + d1) + (d2 + d3);
}

// ---------------------------------------------------------------------------
// Stage 1: KNN on raw points + wFM -> R, sqr. Block 0 additionally computes
// Q[k][f] = sum_c softmax(w_fm2)[c][k]*w_mix1[c]*w_mix2[c][f] once (stage2
// just loads it). Also initializes out with the classifier bias.
// ---------------------------------------------------------------------------
__global__ __launch_bounds__(256)
void stage1_kernel(const float* __restrict__ x, const float* __restrict__ w_fm1,
                   const float* __restrict__ w_fm2, const float* __restrict__ w_mix1,
                   const float* __restrict__ w_mix2, const float* __restrict__ b_cls,
                   float* __restrict__ R, float* __restrict__ sqr,
                   float* __restrict__ Q, float* __restrict__ out) {
    __shared__ float ssq[512];
    __shared__ float swn[KNN];
    __shared__ float wcs[30 * 21];
    __shared__ float smix2[1500];
    const int tid   = threadIdx.x;
    const int bidx  = blockIdx.x;
    const int batch = bidx >> 7;          // 128 blocks per batch
    const float* xb = x + (size_t)batch * 8192;

    if ((bidx & 127) == 0 && tid < 40)
        out[batch * 40 + tid] = b_cls[tid];

    if (tid < KNN) {
        float v[KNN]; float mx = -__builtin_inff();
        #pragma unroll
        for (int k = 0; k < KNN; ++k) { v[k] = w_fm1[k]; mx = fmaxf(mx, v[k]); }
        float s = 0.f;
        #pragma unroll
        for (int k = 0; k < KNN; ++k) { v[k] = __expf(v[k] - mx); s += v[k]; }
        swn[tid] = v[tid] / s;
    }

    if (bidx == 0) {                      // one-time Q prep staging
        for (int e = tid; e < 1500; e += 256) smix2[e] = w_mix2[e];
        if (tid < 30) {
            float wr[KNN]; float mx = -__builtin_inff();
            #pragma unroll
            for (int k = 0; k < KNN; ++k) { wr[k] = w_fm2[tid * KNN + k]; mx = fmaxf(mx, wr[k]); }
            float s = 0.f;
            #pragma unroll
            for (int k = 0; k < KNN; ++k) { wr[k] = __expf(wr[k] - mx); s += wr[k]; }
            const float scale = w_mix1[tid] / s;
            #pragma unroll
            for (int k = 0; k < KNN; ++k) wcs[tid * 21 + k] = wr[k] * scale;
        }
    }

    for (int m = tid; m < 512; m += 256) {
        const float4* p = (const float4*)(xb + m * 16);
        const float4 a0 = p[0], a1 = p[1], a2 = p[2], a3 = p[3];
        ssq[m] = dot16(a0, a1, a2, a3, a0, a1, a2, a3);
    }
    __syncthreads();

    if (bidx == 0) {                      // Q[k][f], written once to workspace
        for (int e = tid; e < KNN * 50; e += 256) {
            const int k = e / 50, f = e - k * 50;
            float acc = 0.f;
            #pragma unroll
            for (int c = 0; c < 30; ++c)
                acc = fmaf(wcs[c * 21 + k], smix2[c * 50 + f], acc);
            Q[e] = acc;
        }
    }

    const int t = tid & 63, w = tid >> 6;
    const int row = bidx * 4 + w;
    const int n = row & 511;

    const float4* xn4 = (const float4*)(xb + n * 16);
    const float4 o0 = xn4[0], o1 = xn4[1], o2 = xn4[2], o3 = xn4[3];
    const float sqn = ssq[n];

    unsigned cd[8];
    #pragma unroll
    for (int i = 0; i < 8; ++i) cd[i] = INFK;

    #pragma unroll
    for (int j = 0; j < 8; ++j) {
        const int m = j * 64 + t;
        const float4* xm4 = (const float4*)(xb + m * 16);
        const float4 a0 = xm4[0], a1 = xm4[1], a2 = xm4[2], a3 = xm4[3];
        const float dot = dot16(o0, o1, o2, o3, a0, a1, a2, a3);
        float vd = fmaxf(sqn + ssq[m] - 2.f * dot, 0.f);   // exact 0 at m==n
        insert8(cd, (__float_as_uint(vd) & 0xFFFFFE00u) | (unsigned)m);
    }

    const int nbrv = merge20(cd, t);

    // gather: lane covers e = j*64+t -> (k = e>>4, d = e&15)
    float nrf[5];
    #pragma unroll
    for (int j = 0; j < 5; ++j) {
        const int e = j * 64 + t;
        const int nb = __shfl(nbrv, e >> 4, 64);
        nrf[j] = xb[nb * 16 + (e & 15)];
    }
    // partial wFM: lane t holds sum over its 5 k's for d = t&15 (k = j*4 + t>>4)
    const int kq = t >> 4;
    float part = 0.f;
    #pragma unroll
    for (int j = 0; j < 5; ++j) part = fmaf(swn[j * 4 + kq], nrf[j], part);
    // butterfly over the 4 duplicate lane groups -> all lanes hold R[t&15]
    part += __shfl_xor(part, 16, 64);
    part += __shfl_xor(part, 32, 64);
    const float racc = part;
    if (t < 16) R[(size_t)row * 16 + t] = racc;

    // ||R||^2 with the SAME 4-chain grouping as dot16 (stage-2 diag -> exact 0)
    float p0 = 0.f, p1 = 0.f, p2 = 0.f, p3 = 0.f;
    #pragma unroll
    for (int d = 0; d < 4; ++d) {
        const float rv = __int_as_float(__builtin_amdgcn_readlane(__float_as_int(racc), d));
        p0 = fmaf(rv, rv, p0);
    }
    #pragma unroll
    for (int d = 4; d < 8; ++d) {
        const float rv = __int_as_float(__builtin_amdgcn_readlane(__float_as_int(racc), d));
        p1 = fmaf(rv, rv, p1);
    }
    #pragma unroll
    for (int d = 8; d < 12; ++d) {
        const float rv = __int_as_float(__builtin_amdgcn_readlane(__float_as_int(racc), d));
        p2 = fmaf(rv, rv, p2);
    }
    #pragma unroll
    for (int d = 12; d < 16; ++d) {
        const float rv = __int_as_float(__builtin_amdgcn_readlane(__float_as_int(racc), d));
        p3 = fmaf(rv, rv, p3);
    }
    if (t == 0) sqr[row] = (p0 + p1) + (p2 + p3);
}

// ---------------------------------------------------------------------------
// Stage 2: KNN on R + fused wFM2.mix2 (via precomputed Q) + manifold dist +
// pool + classifier atomic accumulation.
// ---------------------------------------------------------------------------
__global__ __launch_bounds__(256)
void stage2_kernel(const float* __restrict__ Rg, const float* __restrict__ sqr,
                   const float* __restrict__ Q, const float* __restrict__ m_last,
                   const float* __restrict__ w_cls, float* __restrict__ out) {
    __shared__ float sQ[KNN * 50];
    __shared__ float sM[16 * 50];
    __shared__ float ssq2[512];
    __shared__ float pool4[4];
    const int tid   = threadIdx.x;
    const int bidx  = blockIdx.x;
    const int batch = bidx >> 7;
    const float* Rb = Rg + (size_t)batch * 8192;
    const float* sb = sqr + batch * 512;

    for (int e = tid; e < KNN * 50; e += 256) sQ[e] = Q[e];
    for (int e = tid; e < 16 * 50; e += 256) sM[e] = m_last[e];
    for (int m = tid; m < 512; m += 256) ssq2[m] = sb[m];
    __syncthreads();

    const int t = tid & 63, w = tid >> 6;
    const int row = bidx * 4 + w;
    const int n = row & 511;

    const float4* rn4 = (const float4*)(Rb + n * 16);
    const float4 o0 = rn4[0], o1 = rn4[1], o2 = rn4[2], o3 = rn4[3];
    const float sqn = ssq2[n];

    unsigned cd[8];
    #pragma unroll
    for (int i = 0; i < 8; ++i) cd[i] = INFK;

    #pragma unroll
    for (int j = 0; j < 8; ++j) {
        const int m = j * 64 + t;
        const float4* rm4 = (const float4*)(Rb + m * 16);
        const float4 a0 = rm4[0], a1 = rm4[1], a2 = rm4[2], a3 = rm4[3];
        const float dot = dot16(o0, o1, o2, o3, a0, a1, a2, a3);
        float vd = fmaxf(sqn + ssq2[m] - 2.f * dot, 0.f);  // exact 0 at m==n
        insert8(cd, (__float_as_uint(vd) & 0xFFFFFE00u) | (unsigned)m);
    }

    const int nbrv = merge20(cd, t);

    float nrf[5];
    #pragma unroll
    for (int j = 0; j < 5; ++j) {
        const int e = j * 64 + t;
        const int nb = __shfl(nbrv, e >> 4, 64);
        nrf[j] = Rb[nb * 16 + (e & 15)];
    }

    // lane f<50: v[d] = sum_k NR[k][d]*Q[k][f]; dist = sqrt(sum (v-m)^2 + 1e-8)
    const int f = (t < 50) ? t : 49;
    float q[KNN];
    #pragma unroll
    for (int k = 0; k < KNN; ++k) q[k] = sQ[k * 50 + f];
    float acc = 0.f;
    #pragma unroll
    for (int d = 0; d < 16; ++d) {
        float v = 0.f;
        #pragma unroll
        for (int k = 0; k < KNN; ++k) {
            const int e = k * 16 + d;
            const float nr = __int_as_float(
                __builtin_amdgcn_readlane(__float_as_int(nrf[e >> 6]), e & 63));
            v = fmaf(nr, q[k], v);
        }
        v -= sM[d * 50 + f];
        acc = fmaf(v, v, acc);
    }
    float dist50 = (t < 50) ? sqrtf(acc + 1e-8f) : 0.f;
    #pragma unroll
    for (int off = 32; off >= 1; off >>= 1) dist50 += __shfl_xor(dist50, off, 64);
    if (t == 0) pool4[w] = dist50 * (1.0f / 50.0f);
    __syncthreads();

    if (tid < 40) {
        const int n0 = (bidx * 4) & 511;
        float a = 0.f;
        #pragma unroll
        for (int i = 0; i < 4; ++i)
            a = fmaf(pool4[i], w_cls[(n0 + i) * 40 + tid], a);
        unsafeAtomicAdd(&out[batch * 40 + tid], a);
    }
}

extern "C" void kernel_launch(void* const* d_in, const int* in_sizes, int n_in,
                              void* d_out, int out_size, void* d_ws, size_t ws_size,
                              hipStream_t stream) {
    const float* x      = (const float*)d_in[0];
    const float* w_fm1  = (const float*)d_in[1];
    const float* w_mix1 = (const float*)d_in[2];
    const float* w_fm2  = (const float*)d_in[3];
    const float* w_mix2 = (const float*)d_in[4];
    const float* m_last = (const float*)d_in[5];
    const float* w_cls  = (const float*)d_in[6];
    const float* b_cls  = (const float*)d_in[7];
    float* out = (float*)d_out;

    float* ws   = (float*)d_ws;
    float* R    = ws;                  // 131072 floats
    float* sqrb = ws + 131072;         // 8192 floats
    float* Q    = ws + 139264;         // 1000 floats

    stage1_kernel<<<2048, 256, 0, stream>>>(x, w_fm1, w_fm2, w_mix1, w_mix2,
                                            b_cls, R, sqrb, Q, out);
    stage2_kernel<<<2048, 256, 0, stream>>>(R, sqrb, Q, m_last, w_cls, out);
}

// Round 6
// 117.232 us; speedup vs baseline: 1.2068x; 1.0451x over previous
//
#include <hip/hip_runtime.h>
#include <math.h>

#define KNN  20
#define INFK 0xFFFFFFFFu

typedef _Float16 half8 __attribute__((ext_vector_type(8)));
typedef float    f32x4 __attribute__((ext_vector_type(4)));

// ---- DPP wave64 min-reduction (u32), broadcast via readlane ----------------
#define DPP_MIN_STEP(v, ctrl, rm)                                              \
    {                                                                          \
        unsigned _t = (unsigned)__builtin_amdgcn_update_dpp(                   \
            (int)(v), (int)(v), (ctrl), (rm), 0xf, false);                     \
        (v) = ((v) < _t) ? (v) : _t;                                           \
    }

__device__ __forceinline__ unsigned wave_min_bcast(unsigned v) {
    DPP_MIN_STEP(v, 0x111, 0xf);   // row_shr:1
    DPP_MIN_STEP(v, 0x112, 0xf);   // row_shr:2
    DPP_MIN_STEP(v, 0x114, 0xf);   // row_shr:4
    DPP_MIN_STEP(v, 0x118, 0xf);   // row_shr:8
    DPP_MIN_STEP(v, 0x142, 0xa);   // row_bcast:15
    DPP_MIN_STEP(v, 0x143, 0xc);   // row_bcast:31
    return (unsigned)__builtin_amdgcn_readlane((int)v, 63);
}

#define CE(a, b)                                                               \
    { unsigned _lo = ((a) < (b)) ? (a) : (b);                                  \
      unsigned _hi = ((a) < (b)) ? (b) : (a); (a) = _lo; (b) = _hi; }

__device__ __forceinline__ void insert4(unsigned (&cd)[4], unsigned key) {
    #pragma unroll
    for (int i = 0; i < 4; ++i) CE(cd[i], key);
}

// Batcher odd-even merge of two sorted 4-lists -> sorted 8
__device__ __forceinline__ void merge44(unsigned (&a)[4], unsigned (&b)[4],
                                        unsigned (&o)[8]) {
    CE(a[0], b[0]); CE(a[1], b[1]); CE(a[2], b[2]); CE(a[3], b[3]);
    CE(a[2], b[0]); CE(a[3], b[1]);
    CE(a[1], a[2]); CE(a[3], b[0]); CE(b[1], b[2]);
    o[0] = a[0]; o[1] = a[1]; o[2] = a[2]; o[3] = a[3];
    o[4] = b[0]; o[5] = b[1]; o[6] = b[2]; o[7] = b[3];
}

// 20-round all-register merge; lane r ends holding neighbor index r.
__device__ __forceinline__ int merge20(unsigned (&cd)[8], int t) {
    int nbrv = 0;
    #pragma unroll
    for (int r = 0; r < KNN; ++r) {
        const unsigned bk = wave_min_bcast(cd[0]);
        nbrv = (t == r) ? (int)(bk & 511u) : nbrv;
        const bool win = (cd[0] == bk);
        #pragma unroll
        for (int i = 0; i < 7; ++i) cd[i] = win ? cd[i + 1] : cd[i];
        cd[7] = win ? INFK : cd[7];
    }
    return nbrv;
}

// canonical 4-chain dot; EVERY sq/dot uses this -> m==n diagonal exactly 0
__device__ __forceinline__ float dot16(const float4& o0, const float4& o1,
                                       const float4& o2, const float4& o3,
                                       const float4& a0, const float4& a1,
                                       const float4& a2, const float4& a3) {
    float d0 = 0.f, d1 = 0.f, d2 = 0.f, d3 = 0.f;
    d0 = fmaf(o0.x, a0.x, d0); d0 = fmaf(o0.y, a0.y, d0); d0 = fmaf(o0.z, a0.z, d0); d0 = fmaf(o0.w, a0.w, d0);
    d1 = fmaf(o1.x, a1.x, d1); d1 = fmaf(o1.y, a1.y, d1); d1 = fmaf(o1.z, a1.z, d1); d1 = fmaf(o1.w, a1.w, d1);
    d2 = fmaf(o2.x, a2.x, d2); d2 = fmaf(o2.y, a2.y, d2); d2 = fmaf(o2.z, a2.z, d2); d2 = fmaf(o2.w, a2.w, d2);
    d3 = fmaf(o3.x, a3.x, d3); d3 = fmaf(o3.y, a3.y, d3); d3 = fmaf(o3.z, a3.z, d3); d3 = fmaf(o3.w, a3.w, d3);
    return (d0 + d1) + (d2 + d3);
}

// candidate scan: 8 candidates/lane, packed (dist,idx) keys, sorted-8 result
__device__ __forceinline__ void scan_candidates(const float* __restrict__ base,
                                                const float* __restrict__ ssq,
                                                float sqn, int t,
                                                const float4& o0, const float4& o1,
                                                const float4& o2, const float4& o3,
                                                unsigned (&cd)[8]) {
    unsigned ca[4], cb[4];
    #pragma unroll
    for (int i = 0; i < 4; ++i) { ca[i] = INFK; cb[i] = INFK; }
    #pragma unroll
    for (int j = 0; j < 8; ++j) {
        const int m = j * 64 + t;
        const float4* p = (const float4*)(base + m * 16);
        const float4 a0 = p[0], a1 = p[1], a2 = p[2], a3 = p[3];
        const float dot = dot16(o0, o1, o2, o3, a0, a1, a2, a3);
        float vd = fmaxf(sqn + ssq[m] - 2.f * dot, 0.f);   // exact 0 at m==n
        const unsigned key = (__float_as_uint(vd) & 0xFFFFFE00u) | (unsigned)m;
        if (j < 4) insert4(ca, key); else insert4(cb, key);
    }
    merge44(ca, cb, cd);
}

// ---------------------------------------------------------------------------
// Stage 1: KNN on raw points + wFM -> R, sqr. Block 0 additionally builds the
// per-lane MFMA fragment tables for stage2 (Bfrag: Q in f16, Mfrag: m_last)
// and initializes out with the classifier bias.
// ---------------------------------------------------------------------------
__global__ __launch_bounds__(256)
void stage1_kernel(const float* __restrict__ x, const float* __restrict__ w_fm1,
                   const float* __restrict__ w_fm2, const float* __restrict__ w_mix1,
                   const float* __restrict__ w_mix2, const float* __restrict__ m_last,
                   const float* __restrict__ b_cls,
                   float* __restrict__ R, float* __restrict__ sqr,
                   half8* __restrict__ Bfrag, f32x4* __restrict__ Mfrag,
                   float* __restrict__ out) {
    __shared__ float ssq[512];
    __shared__ float swn[KNN];
    __shared__ float wcs[30 * 21];
    __shared__ float smix2[1500];
    const int tid   = threadIdx.x;
    const int bidx  = blockIdx.x;
    const int batch = bidx >> 7;
    const float* xb = x + (size_t)batch * 8192;

    if ((bidx & 127) == 0 && tid < 40)
        out[batch * 40 + tid] = b_cls[tid];

    if (tid < KNN) {
        float v[KNN]; float mx = -__builtin_inff();
        #pragma unroll
        for (int k = 0; k < KNN; ++k) { v[k] = w_fm1[k]; mx = fmaxf(mx, v[k]); }
        float s = 0.f;
        #pragma unroll
        for (int k = 0; k < KNN; ++k) { v[k] = __expf(v[k] - mx); s += v[k]; }
        swn[tid] = v[tid] / s;
    }

    if (bidx == 0) {
        for (int e = tid; e < 1500; e += 256) smix2[e] = w_mix2[e];
        if (tid < 30) {
            float wr[KNN]; float mx = -__builtin_inff();
            #pragma unroll
            for (int k = 0; k < KNN; ++k) { wr[k] = w_fm2[tid * KNN + k]; mx = fmaxf(mx, wr[k]); }
            float s = 0.f;
            #pragma unroll
            for (int k = 0; k < KNN; ++k) { wr[k] = __expf(wr[k] - mx); s += wr[k]; }
            const float scale = w_mix1[tid] / s;
            #pragma unroll
            for (int k = 0; k < KNN; ++k) wcs[tid * 21 + k] = wr[k] * scale;
        }
    }

    for (int m = tid; m < 512; m += 256) {
        const float4* p = (const float4*)(xb + m * 16);
        const float4 a0 = p[0], a1 = p[1], a2 = p[2], a3 = p[3];
        ssq[m] = dot16(a0, a1, a2, a3, a0, a1, a2, a3);
    }
    __syncthreads();

    if (bidx == 0) {
        // Per-lane fragment tables for stage2's mfma_f32_16x16x32_f16:
        //   A[m=lane&15][k=(lane>>4)*8+j], B[k=(lane>>4)*8+j][n=lane&15],
        //   C/D: col=lane&15, row=(lane>>4)*4+reg.
        const int lane = tid & 63, tile = tid >> 6;
        const int q = lane >> 4, c = lane & 15;
        const int f = tile * 16 + c;
        half8 hb;
        #pragma unroll
        for (int j = 0; j < 8; ++j) {
            const int k = q * 8 + j;
            float val = 0.f;
            if (k < KNN && f < 50) {
                #pragma unroll
                for (int cc = 0; cc < 30; ++cc)
                    val = fmaf(wcs[cc * 21 + k], smix2[cc * 50 + f], val);
            }
            hb[j] = (_Float16)val;
        }
        Bfrag[tile * 64 + lane] = hb;
        f32x4 mf;
        #pragma unroll
        for (int r = 0; r < 4; ++r) {
            const int d = q * 4 + r;
            mf[r] = (f < 50) ? m_last[d * 50 + f] : 0.f;
        }
        Mfrag[tile * 64 + lane] = mf;
    }

    const int t = tid & 63, w = tid >> 6;
    const int row = bidx * 4 + w;
    const int n = row & 511;

    const float4* xn4 = (const float4*)(xb + n * 16);
    const float4 o0 = xn4[0], o1 = xn4[1], o2 = xn4[2], o3 = xn4[3];

    unsigned cd[8];
    scan_candidates(xb, ssq, ssq[n], t, o0, o1, o2, o3, cd);
    const int nbrv = merge20(cd, t);

    // gather: lane covers e = j*64+t -> (k = e>>4, d = e&15)
    float nrf[5];
    #pragma unroll
    for (int j = 0; j < 5; ++j) {
        const int e = j * 64 + t;
        const int nb = __shfl(nbrv, e >> 4, 64);
        nrf[j] = xb[nb * 16 + (e & 15)];
    }
    // partial wFM: lane t sums its 5 k's for d = t&15 (k = j*4 + t>>4)
    const int kq = t >> 4;
    float part = 0.f;
    #pragma unroll
    for (int j = 0; j < 5; ++j) part = fmaf(swn[j * 4 + kq], nrf[j], part);
    part += __shfl_xor(part, 16, 64);
    part += __shfl_xor(part, 32, 64);
    const float racc = part;
    if (t < 16) R[(size_t)row * 16 + t] = racc;

    // ||R||^2 with the SAME 4-chain grouping as dot16 (stage-2 diag -> exact 0)
    float p0 = 0.f, p1 = 0.f, p2 = 0.f, p3 = 0.f;
    #pragma unroll
    for (int d = 0; d < 4; ++d) {
        const float rv = __int_as_float(__builtin_amdgcn_readlane(__float_as_int(racc), d));
        p0 = fmaf(rv, rv, p0);
    }
    #pragma unroll
    for (int d = 4; d < 8; ++d) {
        const float rv = __int_as_float(__builtin_amdgcn_readlane(__float_as_int(racc), d));
        p1 = fmaf(rv, rv, p1);
    }
    #pragma unroll
    for (int d = 8; d < 12; ++d) {
        const float rv = __int_as_float(__builtin_amdgcn_readlane(__float_as_int(racc), d));
        p2 = fmaf(rv, rv, p2);
    }
    #pragma unroll
    for (int d = 12; d < 16; ++d) {
        const float rv = __int_as_float(__builtin_amdgcn_readlane(__float_as_int(racc), d));
        p3 = fmaf(rv, rv, p3);
    }
    if (t == 0) sqr[row] = (p0 + p1) + (p2 + p3);
}

// ---------------------------------------------------------------------------
// Stage 2: KNN on R + MFMA-fused wFM2.mix2 + manifold dist + pool + classify.
// ---------------------------------------------------------------------------
__global__ __launch_bounds__(256)
void stage2_kernel(const float* __restrict__ Rg, const float* __restrict__ sqr,
                   const half8* __restrict__ Bfrag, const f32x4* __restrict__ Mfrag,
                   const float* __restrict__ w_cls, float* __restrict__ out) {
    __shared__ float ssq2[512];
    __shared__ float NRs[4][344];       // [wave][20*17+pad] (stride 17 -> <=2-way)
    __shared__ float pool4[4];
    const int tid   = threadIdx.x;
    const int bidx  = blockIdx.x;
    const int batch = bidx >> 7;
    const float* Rb = Rg + (size_t)batch * 8192;
    const float* sb = sqr + batch * 512;

    for (int m = tid; m < 512; m += 256) ssq2[m] = sb[m];
    __syncthreads();

    const int t = tid & 63, w = tid >> 6;
    const int row = bidx * 4 + w;
    const int n = row & 511;

    const float4* rn4 = (const float4*)(Rb + n * 16);
    const float4 o0 = rn4[0], o1 = rn4[1], o2 = rn4[2], o3 = rn4[3];

    unsigned cd[8];
    scan_candidates(Rb, ssq2, ssq2[n], t, o0, o1, o2, o3, cd);
    const int nbrv = merge20(cd, t);

    // gather neighbor rows and bounce through padded LDS (wave-internal)
    #pragma unroll
    for (int j = 0; j < 5; ++j) {
        const int e = j * 64 + t;
        const int nb = __shfl(nbrv, e >> 4, 64);
        NRs[w][(e >> 4) * 17 + (e & 15)] = Rb[nb * 16 + (e & 15)];
    }

    // A-fragment: A[m = t&15][k = (t>>4)*8+j] = NR[k][m], zero for k >= 20
    const int q = t >> 4, c = t & 15;
    half8 af;
    #pragma unroll
    for (int j = 0; j < 8; ++j) {
        const int k = q * 8 + j;
        af[j] = (k < KNN) ? (_Float16)NRs[w][k * 17 + c] : (_Float16)0.f;
    }

    // 4 f-tiles of 16: v = A(16x32) . B(32x16); dist accumulate
    float dsum = 0.f;
    #pragma unroll
    for (int tile = 0; tile < 4; ++tile) {
        const half8 bf = Bfrag[tile * 64 + t];
        const f32x4 mf = Mfrag[tile * 64 + t];
        f32x4 acc = {0.f, 0.f, 0.f, 0.f};
        acc = __builtin_amdgcn_mfma_f32_16x16x32_f16(af, bf, acc, 0, 0, 0);
        float a2 = 0.f;
        #pragma unroll
        for (int r = 0; r < 4; ++r) {
            const float diff = acc[r] - mf[r];
            a2 = fmaf(diff, diff, a2);
        }
        a2 += __shfl_xor(a2, 16, 64);
        a2 += __shfl_xor(a2, 32, 64);
        const int f = tile * 16 + c;
        dsum += (f < 50) ? sqrtf(a2 + 1e-8f) : 0.f;
    }
    // wave sum counts each f 4x (column replication) -> /4; pooled = /50
    #pragma unroll
    for (int off = 32; off >= 1; off >>= 1) dsum += __shfl_xor(dsum, off, 64);
    if (t == 0) pool4[w] = dsum * (1.0f / 200.0f);
    __syncthreads();

    if (tid < 40) {
        const int n0 = (bidx * 4) & 511;
        float a = 0.f;
        #pragma unroll
        for (int i = 0; i < 4; ++i)
            a = fmaf(pool4[i], w_cls[(n0 + i) * 40 + tid], a);
        unsafeAtomicAdd(&out[batch * 40 + tid], a);
    }
}

extern "C" void kernel_launch(void* const* d_in, const int* in_sizes, int n_in,
                              void* d_out, int out_size, void* d_ws, size_t ws_size,
                              hipStream_t stream) {
    const float* x      = (const float*)d_in[0];
    const float* w_fm1  = (const float*)d_in[1];
    const float* w_mix1 = (const float*)d_in[2];
    const float* w_fm2  = (const float*)d_in[3];
    const float* w_mix2 = (const float*)d_in[4];
    const float* m_last = (const float*)d_in[5];
    const float* w_cls  = (const float*)d_in[6];
    const float* b_cls  = (const float*)d_in[7];
    float* out = (float*)d_out;

    float* ws    = (float*)d_ws;
    float* R     = ws;                        // 131072 floats
    float* sqrb  = ws + 131072;               // 8192 floats
    half8* Bf    = (half8*)(ws + 139264);     // 256 x 16 B = 1024 floats
    f32x4* Mf    = (f32x4*)(ws + 140288);     // 256 x 16 B = 1024 floats

    stage1_kernel<<<2048, 256, 0, stream>>>(x, w_fm1, w_fm2, w_mix1, w_mix2,
                                            m_last, b_cls, R, sqrb, Bf, Mf, out);
    stage2_kernel<<<2048, 256, 0, stream>>>(R, sqrb, Bf, Mf, w_cls, out);
}